// Round 16
// baseline (283.685 us; speedup 1.0000x reference)
//
#include <hip/hip_runtime.h>
#include <hip/hip_bf16.h>

// MetaLA fused pipeline, round 16 = R15 + 32x32x16 MFMA (2382 vs 2075 TF ubench;
// 16 long MFMAs/K-tile instead of 32 short -> MFMA drain -17% in the measured
// serialized LDS+MFMA regime) + scan_phase2 spread over 32 blocks.
//  gemm_rp : 256x256 tile, BK=32, 4-slot LDS ring, counted vmcnt(4), register
//            read-ahead with SGB-pinned interleave; mfma_f32_32x32x16_bf16
//            (C/D: col=lane&31, row=(reg&3)+8*(reg>>2)+4*(lane>>5), m74/m101);
//            A/B frags at row/col=lane&31, k=(lane>>5)*8+e (k-permutation-safe).
//            LDS-transpose sector-dense bf16 epilogue. launch_bounds(512,2).
//  out-proj bf16 -> outln; ln_kernel reads bf16, writes fp32 d_out.

#define HIDDEN 1024
#define HEADS 8
#define HDIM 64
#define INNER 512
#define BATCH 4
#define SEQ 8192
#define ROWS (BATCH*SEQ)
#define NCHUNK 128
#define CHLEN 64

typedef unsigned short u16;
typedef unsigned int u32;
typedef __attribute__((ext_vector_type(8))) short bf16x8;
typedef __attribute__((ext_vector_type(4))) float f32x4;
typedef __attribute__((ext_vector_type(16))) float f32x16;

__device__ __forceinline__ float b2f(u16 u) { return __uint_as_float(((u32)u) << 16); }
__device__ __forceinline__ u16 f2b(float f) {
  u32 u = __float_as_uint(f);
  u32 r = u + 0x7fffu + ((u >> 16) & 1u);  // RNE
  return (u16)(r >> 16);
}
__device__ __forceinline__ u32 pack2(float a, float b) {
  return (u32)f2b(a) | ((u32)f2b(b) << 16);
}

#define GLOAD_LDS16(gp, lp)                                                  \
  __builtin_amdgcn_global_load_lds(                                          \
      (const __attribute__((address_space(1))) u32*)(gp),                    \
      (__attribute__((address_space(3))) u32*)(lp), 16, 0, 0)

// ---------------- prep_xw: x fp32->bf16 (blocks 0..16383) + weight prep (16384..24575) ----
__global__ __launch_bounds__(256) void prep_xw(
    const float* __restrict__ x, u16* __restrict__ xb,
    const float* __restrict__ Wq, const float* __restrict__ Wk,
    const float* __restrict__ Wv, const float* __restrict__ Wo,
    const float* __restrict__ bq, const float* __restrict__ bk,
    const float* __restrict__ bv,
    u16* __restrict__ Wt, u16* __restrict__ Wot, float* __restrict__ bcat) {
  const int b = blockIdx.x;
  if (b < 16384) {
    size_t i = ((size_t)b * 256 + threadIdx.x) * 8;
    float4 a = *(const float4*)(x + i);
    float4 c = *(const float4*)(x + i + 4);
    uint4 w = {pack2(a.x, a.y), pack2(a.z, a.w), pack2(c.x, c.y), pack2(c.z, c.w)};
    *(uint4*)(xb + i) = w;
  } else {
    const int WELEM = HIDDEN * INNER;  // 524288
    int idx = (b - 16384) * 256 + threadIdx.x;
    if (idx < 3 * WELEM) {
      int z = idx / WELEM;
      int rem = idx - z * WELEM;  // n*1024 + k
      int n = rem >> 10;
      int k = rem & 1023;
      const float* W = (z == 0) ? Wq : (z == 1) ? Wk : Wv;
      Wt[idx] = f2b(W[k * INNER + n]);
    } else {
      int rem = idx - 3 * WELEM;  // n*512 + k
      int n = rem >> 9;
      int k = rem & 511;
      Wot[rem] = f2b(Wo[k * HIDDEN + n]);
    }
    if (idx < 3 * INNER) {
      int z = idx >> 9;
      int n = idx & 511;
      bcat[idx] = (z == 0) ? bq[n] : (z == 1) ? bk[n] : bv[n];
    }
  }
}

// ---------------- prep_w (fallback path only) ----------------
__global__ __launch_bounds__(256) void prep_w(
    const float* __restrict__ Wq, const float* __restrict__ Wk,
    const float* __restrict__ Wv, const float* __restrict__ Wo,
    const float* __restrict__ bq, const float* __restrict__ bk,
    const float* __restrict__ bv,
    u16* __restrict__ Wt, u16* __restrict__ Wot, float* __restrict__ bcat) {
  const int WELEM = HIDDEN * INNER;
  int idx = blockIdx.x * 256 + threadIdx.x;
  if (idx < 3 * WELEM) {
    int z = idx / WELEM;
    int rem = idx - z * WELEM;
    int n = rem >> 10;
    int k = rem & 1023;
    const float* W = (z == 0) ? Wq : (z == 1) ? Wk : Wv;
    Wt[idx] = f2b(W[k * INNER + n]);
  } else {
    int rem = idx - 3 * WELEM;
    int n = rem >> 9;
    int k = rem & 511;
    Wot[rem] = f2b(Wo[k * HIDDEN + n]);
  }
  if (idx < 3 * INNER) {
    int z = idx >> 9;
    int n = idx & 511;
    bcat[idx] = (z == 0) ? bq[n] : (z == 1) ? bk[n] : bv[n];
  }
}

// ---------------- gemm_rp: 256x256, BK=32, 4-slot ring, 32x32x16 MFMA ----------------
// A: [M][K] bf16, Bt: [N][K] bf16 (row n = output col), out = A@Bt^T + bias (bf16 out).
// SPLIT3: N=1536, route 512-col groups to out0/1/2 ([M][512] bf16); else out0 [M][N] bf16.
template <int K, bool SPLIT3>
__global__ __launch_bounds__(512, 2) void gemm_rp(
    const u16* __restrict__ A, const u16* __restrict__ Bt,
    const float* __restrict__ bias,
    void* __restrict__ out0, void* __restrict__ out1, void* __restrict__ out2,
    int nTilesN) {
  constexpr int NT = K / 32;  // K-tiles; >= 8, even
  // slot: A 256x32 swizzled (8192 u16) | B 256x32 swizzled (8192 u16) = 32KB
  __shared__ u16 lds[4][16384];

  // bijective XCD-chunked swizzle (nwg % 8 == 0); consecutive lin share A-panel
  const int nwg = gridDim.x;
  const int chunk = nwg >> 3;
  const int bid = blockIdx.x;
  const int lin = (bid & 7) * chunk + (bid >> 3);
  const int nt = lin % nTilesN;
  const int mt = lin / nTilesN;
  const int m0 = mt * 256, n0 = nt * 256;
  const int N = nTilesN * 256;

  const int tid = threadIdx.x;
  const int lane = tid & 63;
  const int w = tid >> 6;   // 0..7
  const int wm = w >> 2;    // 0..1  (M half: 128 rows)
  const int wn = w & 3;     // 0..3  (N quarter: 64 cols)

  // ---- staging geometry (pre-swizzled global source, linear LDS dest) ----
  const int rt = tid >> 2;                            // row within round
  const int cg = (((tid & 3) << 3)) ^ (((rt >> 1) & 3) << 3);
  const u16* Ag = A + (size_t)(m0 + rt) * K + cg;
  const u16* Bg = Bt + (size_t)(n0 + rt) * K + cg;
  const int ldst = w * 512;  // wave-uniform; HW adds lane*16B

#define STAGE_AB(slot, kt)                                                    \
  {                                                                           \
    GLOAD_LDS16(Ag + (size_t)(kt) * 32, &lds[slot][ldst]);                    \
    GLOAD_LDS16(Ag + (size_t)(kt) * 32 + (size_t)128 * K,                     \
                &lds[slot][4096 + ldst]);                                     \
    GLOAD_LDS16(Bg + (size_t)(kt) * 32, &lds[slot][8192 + ldst]);             \
    GLOAD_LDS16(Bg + (size_t)(kt) * 32 + (size_t)128 * K,                     \
                &lds[slot][12288 + ldst]);                                    \
  }

  // ---- read-side (32x32x16 fragments): elem (row,c) at row*32 + (c ^ (((row>>1)&3)<<3))
  // A frag (row-tile it, k-step s): row = wm*128 + it*32 + r31, c = s*16 + hi8 + 0..7
  // B frag (col-tile jt, k-step s): row = wn*64 + jt*32 + r31, same c.
  const int r31 = lane & 31;
  const int hi8 = (lane >> 5) << 3;
  const int xr = ((r31 >> 1) & 3) << 3;
  const int xs0 = hi8 ^ xr;
  const int xs1 = (16 + hi8) ^ xr;
  const int aO = (wm * 128 + r31) * 32;          // + it*1024 + xs[s]
  const int bO = 8192 + (wn * 64 + r31) * 32;    // + jt*1024 + xs[s]

  f32x16 acc[4][2] = {};
  // frag indices: A ii = it*2+s (it 0..3); B jj = jt*2+s (jt 0..1)
  bf16x8 r0_a[8], r0_b[4], r1_a[8], r1_b[4];  // two named operand sets (rule #20)

#define DSREAD(da, db, slot)                                                   \
  {                                                                            \
    const u16* sl = &lds[slot][0];                                             \
    _Pragma("unroll") for (int it = 0; it < 4; it++) {                         \
      da[it * 2] = *(const bf16x8*)&sl[aO + it * 1024 + xs0];                  \
      da[it * 2 + 1] = *(const bf16x8*)&sl[aO + it * 1024 + xs1];              \
    }                                                                          \
    _Pragma("unroll") for (int jt = 0; jt < 2; jt++) {                         \
      db[jt * 2] = *(const bf16x8*)&sl[bO + jt * 1024 + xs0];                  \
      db[jt * 2 + 1] = *(const bf16x8*)&sl[bO + jt * 1024 + xs1];              \
    }                                                                          \
  }

#define MFMA_SET(sa, sb)                                                       \
  {                                                                            \
    __builtin_amdgcn_s_setprio(1);                                             \
    _Pragma("unroll") for (int it = 0; it < 4; it++)                           \
        _Pragma("unroll") for (int jt = 0; jt < 2; jt++)                       \
            _Pragma("unroll") for (int s = 0; s < 2; s++)                      \
                acc[it][jt] = __builtin_amdgcn_mfma_f32_32x32x16_bf16(         \
                    sa[it * 2 + s], sb[jt * 2 + s], acc[it][jt], 0, 0, 0);     \
    __builtin_amdgcn_s_setprio(0);                                             \
  }

  // Compute tile t from (sa,sb) while reading tile t+1 into (da,db); SGB pins
  // the emitted order to {4 B ds_read, then 4x{2 A ds_read, 4 MFMA}}.
#define MFMA_RD(sa, sb, da, db, slot)                                          \
  {                                                                            \
    const u16* sl = &lds[slot][0];                                             \
    __builtin_amdgcn_s_setprio(1);                                             \
    _Pragma("unroll") for (int jt = 0; jt < 2; jt++) {                         \
      db[jt * 2] = *(const bf16x8*)&sl[bO + jt * 1024 + xs0];                  \
      db[jt * 2 + 1] = *(const bf16x8*)&sl[bO + jt * 1024 + xs1];              \
    }                                                                          \
    _Pragma("unroll") for (int it = 0; it < 4; it++) {                         \
      da[it * 2] = *(const bf16x8*)&sl[aO + it * 1024 + xs0];                  \
      da[it * 2 + 1] = *(const bf16x8*)&sl[aO + it * 1024 + xs1];              \
      _Pragma("unroll") for (int jt = 0; jt < 2; jt++)                         \
          _Pragma("unroll") for (int s = 0; s < 2; s++)                        \
              acc[it][jt] = __builtin_amdgcn_mfma_f32_32x32x16_bf16(           \
                  sa[it * 2 + s], sb[jt * 2 + s], acc[it][jt], 0, 0, 0);       \
    }                                                                          \
    __builtin_amdgcn_s_setprio(0);                                             \
    __builtin_amdgcn_sched_group_barrier(0x100, 4, 0); /* 4 B ds_read */       \
    _Pragma("unroll") for (int it = 0; it < 4; it++) {                         \
      __builtin_amdgcn_sched_group_barrier(0x100, 2, 0); /* 2 A ds_read */     \
      __builtin_amdgcn_sched_group_barrier(0x8, 4, 0);   /* 4 MFMA */          \
    }                                                                          \
  }

#define SYNCB                                                                  \
  {                                                                            \
    __builtin_amdgcn_sched_barrier(0);                                         \
    __builtin_amdgcn_s_barrier();                                              \
    __builtin_amdgcn_sched_barrier(0);                                         \
  }

#define VM4 asm volatile("s_waitcnt vmcnt(4)" ::: "memory")
#define VM0 asm volatile("s_waitcnt vmcnt(0)" ::: "memory")

  // prologue: stage tiles 0,1,2; vmcnt(4) -> tiles 0,1 landed (tile2 in flight);
  // barrier; read tile0 into set0.
  STAGE_AB(0, 0);
  STAGE_AB(1, 1);
  STAGE_AB(2, 2);
  VM4;
  SYNCB;
  DSREAD(r0_a, r0_b, 0);

  // steady state, pairs (t, t+1), t <= NT-6:
  //   half A: STAGE(t+3); {MFMA tile t  || read t+1 -> set1}; VM4 (t+2 landed); barrier
  //   half B: STAGE(t+4); {MFMA tile t+1|| read t+2 -> set0}; VM4 (t+3 landed); barrier
  for (int t = 0; t + 6 <= NT; t += 2) {
    STAGE_AB((t + 3) & 3, t + 3);
    MFMA_RD(r0_a, r0_b, r1_a, r1_b, (t + 1) & 3);
    VM4;
    SYNCB;
    STAGE_AB((t + 4) & 3, t + 4);
    MFMA_RD(r1_a, r1_b, r0_a, r0_b, (t + 2) & 3);
    VM4;
    SYNCB;
  }
  // tail: tiles NT-4 .. NT-1
  STAGE_AB((NT - 1) & 3, NT - 1);          // last stage
  MFMA_RD(r0_a, r0_b, r1_a, r1_b, (NT - 3) & 3);  // tile NT-4, read NT-3
  VM4;                                     // tile NT-2 landed (only NT-1 in flight)
  SYNCB;
  MFMA_RD(r1_a, r1_b, r0_a, r0_b, (NT - 2) & 3);  // tile NT-3, read NT-2
  VM0;                                     // tile NT-1 landed
  SYNCB;
  MFMA_RD(r0_a, r0_b, r1_a, r1_b, (NT - 1) & 3);  // tile NT-2, read NT-1
  MFMA_SET(r1_a, r1_b);                    // tile NT-1
  SYNCB;                                   // frees LDS for the epilogue
#undef DSREAD
#undef MFMA_SET
#undef MFMA_RD
#undef SYNCB
#undef VM4
#undef VM0
#undef STAGE_AB

  // ---- epilogue: wave-local LDS transpose -> sector-dense coalesced bf16 stores ----
  // acc[it][jt] is a 32x32 tile: elem (row,col): col = lane&31,
  // row = (reg&3) + 8*(reg>>2) + 4*(lane>>5)  [m74/m101 verified].
  // Per pass it: dump both jt tiles into [32][68] f32, read back row-major.
  float* fl = (float*)(&lds[0][0]) + w * 2176;  // [32][68] = 8704 B/wave, 8 waves = 69.6 KB
  const int zsel = SPLIT3 ? ((n0 + wn * 64) >> 9) : 0;
  u16* ob = SPLIT3 ? (u16*)((zsel == 0) ? out0 : (zsel == 1) ? out1 : out2)
                   : (u16*)out0;
  const int OC = SPLIT3 ? INNER : N;
  const int colloc = (lane & 7) * 8;
  const int gcol = (SPLIT3 ? ((n0 + wn * 64) & 511) : (n0 + wn * 64)) + colloc;
  const int lrowr = lane >> 3;
  const int hi4 = (lane >> 5) << 2;
  float bvj[2];
#pragma unroll
  for (int jt = 0; jt < 2; jt++) bvj[jt] = bias[n0 + wn * 64 + jt * 32 + r31];

#pragma unroll
  for (int it = 0; it < 4; ++it) {
#pragma unroll
    for (int jt = 0; jt < 2; ++jt) {
#pragma unroll
      for (int r = 0; r < 16; ++r) {
        int lrow = (r & 3) + ((r >> 2) << 3) + hi4;
        fl[lrow * 68 + jt * 32 + r31] = acc[it][jt][r] + bvj[jt];
      }
    }
#pragma unroll
    for (int inst = 0; inst < 4; ++inst) {
      int lr = inst * 8 + lrowr;
      float4 f0 = *(float4*)&fl[lr * 68 + colloc];
      float4 f1 = *(float4*)&fl[lr * 68 + colloc + 4];
      uint4 wv = {pack2(f0.x, f0.y), pack2(f0.z, f0.w),
                  pack2(f1.x, f1.y), pack2(f1.z, f1.w)};
      size_t grow = (size_t)(m0 + wm * 128 + it * 32 + lr);
      *(uint4*)&ob[grow * OC + gcol] = wv;
    }
  }
}

// ---------------- legacy 128^2 GEMM (fp32 A staging) — small-ws fallback ----------------
template <bool A_BF16>
__global__ __launch_bounds__(256) void gemm128(
    const void* __restrict__ Aany, const u16* __restrict__ BtBase,
    const float* __restrict__ bias0, const float* __restrict__ bias1,
    const float* __restrict__ bias2,
    void* __restrict__ out0, void* __restrict__ out1, void* __restrict__ out2,
    int K) {
  __shared__ u16 As[128 * 32];
  __shared__ u16 Bs[128 * 32];
  const int N = gridDim.x * 128;
  const int z = blockIdx.z;
  const u16* Bt = BtBase + (size_t)z * N * K;
  const float* bias = (z == 0) ? bias0 : (z == 1) ? bias1 : bias2;
  void* Out = (z == 0) ? out0 : (z == 1) ? out1 : out2;
  const int tid = threadIdx.x;
  const int m0 = blockIdx.y * 128;
  const int n0 = blockIdx.x * 128;
  const int lane = tid & 63;
  const int wid = tid >> 6;
  const int wm = wid >> 1, wn = wid & 1;
  const int r16 = lane & 15, kq = lane >> 4;
  const int r = tid >> 1;
  const int half = tid & 1;
  f32x4 acc[4][4] = {};
  for (int k0 = 0; k0 < K; k0 += 32) {
    __syncthreads();
    if (A_BF16) {
      const u16* Ab = (const u16*)Aany;
      const int4* src = (const int4*)(Ab + (size_t)(m0 + r) * K + k0 + half * 16);
      int4 v0 = src[0];
      int4 v1 = src[1];
      *(int4*)&As[r * 32 + half * 16] = v0;
      *(int4*)&As[r * 32 + half * 16 + 8] = v1;
    } else {
      const float* Af = (const float*)Aany;
      const float4* src = (const float4*)(Af + (size_t)(m0 + r) * K + k0 + half * 16);
      float4 f0 = src[0], f1 = src[1], f2 = src[2], f3 = src[3];
      uint4 w0 = {pack2(f0.x, f0.y), pack2(f0.z, f0.w), pack2(f1.x, f1.y), pack2(f1.z, f1.w)};
      uint4 w1 = {pack2(f2.x, f2.y), pack2(f2.z, f2.w), pack2(f3.x, f3.y), pack2(f3.z, f3.w)};
      *(uint4*)&As[r * 32 + half * 16] = w0;
      *(uint4*)&As[r * 32 + half * 16 + 8] = w1;
    }
    {
      const int4* src = (const int4*)(Bt + (size_t)(n0 + r) * K + k0 + half * 16);
      int4 v0 = src[0];
      int4 v1 = src[1];
      *(int4*)&Bs[r * 32 + half * 16] = v0;
      *(int4*)&Bs[r * 32 + half * 16 + 8] = v1;
    }
    __syncthreads();
    bf16x8 a[4], b[4];
#pragma unroll
    for (int i = 0; i < 4; i++)
      a[i] = *(const bf16x8*)&As[(wm * 64 + i * 16 + r16) * 32 + kq * 8];
#pragma unroll
    for (int j = 0; j < 4; j++)
      b[j] = *(const bf16x8*)&Bs[(wn * 64 + j * 16 + r16) * 32 + kq * 8];
#pragma unroll
    for (int i = 0; i < 4; i++)
#pragma unroll
      for (int j = 0; j < 4; j++)
        acc[i][j] = __builtin_amdgcn_mfma_f32_16x16x32_bf16(a[i], b[j], acc[i][j], 0, 0, 0);
  }
#pragma unroll
  for (int j = 0; j < 4; j++) {
    int col = n0 + wn * 64 + j * 16 + r16;
    float bv = bias[col];
#pragma unroll
    for (int i = 0; i < 4; i++) {
#pragma unroll
      for (int q = 0; q < 4; q++) {
        int row = m0 + wm * 64 + i * 16 + kq * 4 + q;
        float v = acc[i][j][q] + bv;
        ((u16*)Out)[(size_t)row * N + col] = f2b(v);
      }
    }
  }
}

// ---------------- attn: softmax over heads of (q.k)/8 ----------------
__global__ __launch_bounds__(256) void attn_kernel(
    const u16* __restrict__ qb, const u16* __restrict__ kb,
    float* __restrict__ attn) {
  int lane = threadIdx.x & 63;
  int wid = threadIdx.x >> 6;
  size_t t = (size_t)blockIdx.x * 4 + wid;
  int4 qv = *(const int4*)(qb + t * INNER + lane * 8);
  int4 kv = *(const int4*)(kb + t * INNER + lane * 8);
  const u16* qu = (const u16*)&qv;
  const u16* ku = (const u16*)&kv;
  float s = 0.f;
#pragma unroll
  for (int j = 0; j < 8; j++) s += b2f(qu[j]) * b2f(ku[j]);
  s += __shfl_xor(s, 1);
  s += __shfl_xor(s, 2);
  s += __shfl_xor(s, 4);
  s *= 0.125f;
  float mx = s;
  mx = fmaxf(mx, __shfl_xor(mx, 8));
  mx = fmaxf(mx, __shfl_xor(mx, 16));
  mx = fmaxf(mx, __shfl_xor(mx, 32));
  float e = __expf(s - mx);
  float sm = e;
  sm += __shfl_xor(sm, 8);
  sm += __shfl_xor(sm, 16);
  sm += __shfl_xor(sm, 32);
  float a = e / sm;
  if ((lane & 7) == 0) attn[t * HEADS + (lane >> 3)] = a;
}

// ---------------- scan ----------------
__global__ __launch_bounds__(512) void scan_phase1(
    const u16* __restrict__ vb, const float* __restrict__ attn,
    const float* __restrict__ alpha, float* __restrict__ ends) {
  int hd = threadIdx.x;
  int h = hd >> 6;
  int c = blockIdx.x, b = blockIdx.y;
  float decay = 1.f / (1.f + __expf(-alpha[hd]));
  float om = 1.f - decay;
  size_t base = (size_t)b * SEQ + (size_t)c * CHLEN;
  float st = 0.f;
#pragma unroll 8
  for (int i = 0; i < CHLEN; i++) {
    size_t t = base + i;
    float a = attn[t * HEADS + h];
    float v = b2f(vb[t * INNER + hd]);
    st = decay * st + om * a * v;
  }
  ends[((size_t)b * NCHUNK + c) * INNER + hd] = st;
}

__global__ __launch_bounds__(64) void scan_phase2(
    const float* __restrict__ ends, const float* __restrict__ alpha,
    float* __restrict__ carries) {
  int hd = blockIdx.x * 64 + threadIdx.x;
  int b = blockIdx.y;
  float decay = 1.f / (1.f + __expf(-alpha[hd]));
  float dL = __powf(decay, (float)CHLEN);
  float carry = 0.f;
#pragma unroll 8
  for (int c = 0; c < NCHUNK; c++) {
    size_t idx = ((size_t)b * NCHUNK + c) * INNER + hd;
    carries[idx] = carry;
    carry = dL * carry + ends[idx];
  }
}

__global__ __launch_bounds__(512) void scan_phase3(
    const u16* __restrict__ qb, const u16* __restrict__ vb,
    const float* __restrict__ attn, const float* __restrict__ alpha,
    const float* __restrict__ augp, const float* __restrict__ carries,
    u16* __restrict__ outpre) {
  int hd = threadIdx.x;
  int h = hd >> 6;
  int c = blockIdx.x, b = blockIdx.y;
  float decay = 1.f / (1.f + __expf(-alpha[hd]));
  float om = 1.f - decay;
  float ap = augp[hd];
  float st = carries[((size_t)b * NCHUNK + c) * INNER + hd];
  size_t base = (size_t)b * SEQ + (size_t)c * CHLEN;
#pragma unroll 4
  for (int i = 0; i < CHLEN; i++) {
    size_t t = base + i;
    float a = attn[t * HEADS + h];
    float v = b2f(vb[t * INNER + hd]);
    st = decay * st + om * a * v;
    float q = b2f(qb[t * INNER + hd]);
    float aug = 1.f / (1.f + __expf(-q * ap));
    outpre[t * INNER + hd] = f2b(q * st + aug);
  }
}

// ---------------- LayerNorm: bf16 in -> fp32 out ----------------
__global__ __launch_bounds__(256) void ln_kernel(
    const u16* __restrict__ outln, float* __restrict__ out,
    const float* __restrict__ lns, const float* __restrict__ lnb) {
  size_t row = blockIdx.x;
  int tid = threadIdx.x;
  uint2 rv = *(const uint2*)(outln + row * HIDDEN + tid * 4);
  const u16* p = (const u16*)&rv;
  float v0 = b2f(p[0]), v1 = b2f(p[1]), v2 = b2f(p[2]), v3 = b2f(p[3]);
  float s = v0 + v1 + v2 + v3;
  float ss = v0 * v0 + v1 * v1 + v2 * v2 + v3 * v3;
#pragma unroll
  for (int m = 1; m < 64; m <<= 1) {
    s += __shfl_xor(s, m);
    ss += __shfl_xor(ss, m);
  }
  __shared__ float sb[4], ssb[4];
  int lane = tid & 63, wid = tid >> 6;
  if (lane == 0) {
    sb[wid] = s;
    ssb[wid] = ss;
  }
  __syncthreads();
  s = sb[0] + sb[1] + sb[2] + sb[3];
  ss = ssb[0] + ssb[1] + ssb[2] + ssb[3];
  float mean = s * (1.f / HIDDEN);
  float var = ss * (1.f / HIDDEN) - mean * mean;
  float rstd = rsqrtf(var + 1e-6f);
  float4 sc = *(const float4*)(lns + tid * 4);
  float4 bi = *(const float4*)(lnb + tid * 4);
  float4 o;
  o.x = (v0 - mean) * rstd * sc.x + bi.x;
  o.y = (v1 - mean) * rstd * sc.y + bi.y;
  o.z = (v2 - mean) * rstd * sc.z + bi.z;
  o.w = (v3 - mean) * rstd * sc.w + bi.w;
  *(float4*)(out + row * HIDDEN + tid * 4) = o;
}

extern "C" void kernel_launch(void* const* d_in, const int* in_sizes, int n_in,
                              void* d_out, int out_size, void* d_ws, size_t ws_size,
                              hipStream_t stream) {
  const float* x = (const float*)d_in[0];
  const float* Wq = (const float*)d_in[1];
  const float* bq = (const float*)d_in[2];
  const float* Wk = (const float*)d_in[3];
  const float* bk = (const float*)d_in[4];
  const float* Wv = (const float*)d_in[5];
  const float* bv = (const float*)d_in[6];
  const float* Wo = (const float*)d_in[7];
  const float* bo = (const float*)d_in[8];
  const float* alpha = (const float*)d_in[9];
  const float* augp = (const float*)d_in[10];
  const float* lns = (const float*)d_in[11];
  const float* lnb = (const float*)d_in[12];

  char* ws = (char*)d_ws;
  const bool fast = ws_size >= 175118336ull;

  if (fast) {
    u16* xb = (u16*)(ws + 0);                 // 67.1 MB (reused as outln)
    u16* qb = (u16*)(ws + 67108864);          // 33.5 MB
    u16* kb = (u16*)(ws + 100663296);         // 33.5 MB (reused as outpre)
    u16* vb = (u16*)(ws + 134217728);         // 33.5 MB
    u16* Wt = (u16*)(ws + 167772160);         // 3 MB, [1536][1024]
    u16* Wot = (u16*)(ws + 170917888);        // 1 MB, [1024][512]
    float* bcat = (float*)(ws + 171966464);   // 6 KB
    float* attn = (float*)(ws + 171972608);   // 1 MB
    float* ends = (float*)(ws + 173021184);   // 1 MB
    float* car = (float*)(ws + 174069760);    // 1 MB
    u16* outpre = kb;
    u16* outln = xb;  // xb dead after QKV gemm

    prep_xw<<<24576, 256, 0, stream>>>(x, xb, Wq, Wk, Wv, Wo, bq, bk, bv,
                                       Wt, Wot, bcat);

    // QKV: M=32768, N=1536 -> 128*6 = 768 blocks of 512 thr
    gemm_rp<HIDDEN, true><<<768, 512, 0, stream>>>(
        xb, Wt, bcat, qb, kb, vb, 6);

    attn_kernel<<<ROWS / 4, 256, 0, stream>>>(qb, kb, attn);
    scan_phase1<<<dim3(NCHUNK, BATCH), 512, 0, stream>>>(vb, attn, alpha, ends);
    scan_phase2<<<dim3(8, BATCH), 64, 0, stream>>>(ends, alpha, car);
    scan_phase3<<<dim3(NCHUNK, BATCH), 512, 0, stream>>>(qb, vb, attn, alpha, augp, car, outpre);

    // out: M=32768, N=1024 -> 128*4 = 512 blocks, bf16 -> outln
    gemm_rp<INNER, false><<<512, 512, 0, stream>>>(
        outpre, Wot, bo, outln, outln, outln, 4);

    ln_kernel<<<ROWS, 256, 0, stream>>>(outln, (float*)d_out, lns, lnb);
  } else {
    // fallback layout (108 MB): qb@0, vb@33.5, kb@67 (outpre); outln spans qb+vb
    u16* qb = (u16*)(ws + 0);
    u16* vb = (u16*)(ws + 33554432);
    u16* kb = (u16*)(ws + 67108864);
    u16* Wt = (u16*)(ws + 100663296);
    u16* Wot = (u16*)(ws + 103809024);
    float* bcat = (float*)(ws + 104845312);
    float* attn = (float*)(ws + 104857600);
    float* ends = (float*)(ws + 105906176);
    float* car = (float*)(ws + 106954752);
    u16* outpre = kb;
    u16* outln = (u16*)(ws + 0);  // qb+vb dead after scan3

    prep_w<<<8192, 256, 0, stream>>>(Wq, Wk, Wv, Wo, bq, bk, bv, Wt, Wot, bcat);
    gemm128<false><<<dim3(4, 256, 3), 256, 0, stream>>>(
        x, Wt, bq, bk, bv, qb, kb, vb, HIDDEN);
    attn_kernel<<<ROWS / 4, 256, 0, stream>>>(qb, kb, attn);
    scan_phase1<<<dim3(NCHUNK, BATCH), 512, 0, stream>>>(vb, attn, alpha, ends);
    scan_phase2<<<dim3(8, BATCH), 64, 0, stream>>>(ends, alpha, car);
    scan_phase3<<<dim3(NCHUNK, BATCH), 512, 0, stream>>>(qb, vb, attn, alpha, augp, car, outpre);
    gemm_rp<INNER, false><<<512, 512, 0, stream>>>(
        outpre, Wot, bo, outln, outln, outln, 4);
    ln_kernel<<<ROWS, 256, 0, stream>>>(outln, (float*)d_out, lns, lnb);
  }
}

// Round 17
// 266.830 us; speedup vs baseline: 1.0632x; 1.0632x over previous
//
#include <hip/hip_runtime.h>
#include <hip/hip_bf16.h>

// MetaLA fused pipeline, round 17 = exact revert to round 15 (best verified:
// 267.9 us). R16's 32x32x16 MFMA regressed: 32-lane/32-row fragment reads have
// an inherent 4-way LDS bank conflict (row stride 64B = 4/8 slots; 2-bit chunk
// XOR can't spread 32 rows) -> SQ_LDS_BANK_CONFLICT 786K->10.2M, eating the
// +15% MFMA-rate gain. 16x16 geometry (16 rows x 2 k-groups) is the conflict-
// free match for the (row>>1)&3 swizzle under global_load_lds's linear dest.
// GEMM plateau (36-38% MfmaUtil, ~850 TF) stands across 8 schedule variants;
// all non-GEMM stages at HBM floor.

#define HIDDEN 1024
#define HEADS 8
#define HDIM 64
#define INNER 512
#define BATCH 4
#define SEQ 8192
#define ROWS (BATCH*SEQ)
#define NCHUNK 128
#define CHLEN 64

typedef unsigned short u16;
typedef unsigned int u32;
typedef __attribute__((ext_vector_type(8))) short bf16x8;
typedef __attribute__((ext_vector_type(4))) float f32x4;

__device__ __forceinline__ float b2f(u16 u) { return __uint_as_float(((u32)u) << 16); }
__device__ __forceinline__ u16 f2b(float f) {
  u32 u = __float_as_uint(f);
  u32 r = u + 0x7fffu + ((u >> 16) & 1u);  // RNE
  return (u16)(r >> 16);
}
__device__ __forceinline__ u32 pack2(float a, float b) {
  return (u32)f2b(a) | ((u32)f2b(b) << 16);
}

#define GLOAD_LDS16(gp, lp)                                                  \
  __builtin_amdgcn_global_load_lds(                                          \
      (const __attribute__((address_space(1))) u32*)(gp),                    \
      (__attribute__((address_space(3))) u32*)(lp), 16, 0, 0)

// ---------------- prep_xw: x fp32->bf16 (blocks 0..16383) + weight prep (16384..24575) ----
__global__ __launch_bounds__(256) void prep_xw(
    const float* __restrict__ x, u16* __restrict__ xb,
    const float* __restrict__ Wq, const float* __restrict__ Wk,
    const float* __restrict__ Wv, const float* __restrict__ Wo,
    const float* __restrict__ bq, const float* __restrict__ bk,
    const float* __restrict__ bv,
    u16* __restrict__ Wt, u16* __restrict__ Wot, float* __restrict__ bcat) {
  const int b = blockIdx.x;
  if (b < 16384) {
    size_t i = ((size_t)b * 256 + threadIdx.x) * 8;
    float4 a = *(const float4*)(x + i);
    float4 c = *(const float4*)(x + i + 4);
    uint4 w = {pack2(a.x, a.y), pack2(a.z, a.w), pack2(c.x, c.y), pack2(c.z, c.w)};
    *(uint4*)(xb + i) = w;
  } else {
    const int WELEM = HIDDEN * INNER;  // 524288
    int idx = (b - 16384) * 256 + threadIdx.x;
    if (idx < 3 * WELEM) {
      int z = idx / WELEM;
      int rem = idx - z * WELEM;  // n*1024 + k
      int n = rem >> 10;
      int k = rem & 1023;
      const float* W = (z == 0) ? Wq : (z == 1) ? Wk : Wv;
      Wt[idx] = f2b(W[k * INNER + n]);
    } else {
      int rem = idx - 3 * WELEM;  // n*512 + k
      int n = rem >> 9;
      int k = rem & 511;
      Wot[rem] = f2b(Wo[k * HIDDEN + n]);
    }
    if (idx < 3 * INNER) {
      int z = idx >> 9;
      int n = idx & 511;
      bcat[idx] = (z == 0) ? bq[n] : (z == 1) ? bk[n] : bv[n];
    }
  }
}

// ---------------- prep_w (fallback path only) ----------------
__global__ __launch_bounds__(256) void prep_w(
    const float* __restrict__ Wq, const float* __restrict__ Wk,
    const float* __restrict__ Wv, const float* __restrict__ Wo,
    const float* __restrict__ bq, const float* __restrict__ bk,
    const float* __restrict__ bv,
    u16* __restrict__ Wt, u16* __restrict__ Wot, float* __restrict__ bcat) {
  const int WELEM = HIDDEN * INNER;
  int idx = blockIdx.x * 256 + threadIdx.x;
  if (idx < 3 * WELEM) {
    int z = idx / WELEM;
    int rem = idx - z * WELEM;
    int n = rem >> 10;
    int k = rem & 1023;
    const float* W = (z == 0) ? Wq : (z == 1) ? Wk : Wv;
    Wt[idx] = f2b(W[k * INNER + n]);
  } else {
    int rem = idx - 3 * WELEM;
    int n = rem >> 9;
    int k = rem & 511;
    Wot[rem] = f2b(Wo[k * HIDDEN + n]);
  }
  if (idx < 3 * INNER) {
    int z = idx >> 9;
    int n = idx & 511;
    bcat[idx] = (z == 0) ? bq[n] : (z == 1) ? bk[n] : bv[n];
  }
}

// ---------------- gemm_rp: 256x256, BK=32, 4-slot ring, interleaved read-ahead ----------------
// A: [M][K] bf16, Bt: [N][K] bf16 (row n = output col), out = A@Bt^T + bias (bf16 out).
// SPLIT3: N=1536, route 512-col groups to out0/1/2 ([M][512] bf16); else out0 [M][N] bf16.
template <int K, bool SPLIT3>
__global__ __launch_bounds__(512, 2) void gemm_rp(
    const u16* __restrict__ A, const u16* __restrict__ Bt,
    const float* __restrict__ bias,
    void* __restrict__ out0, void* __restrict__ out1, void* __restrict__ out2,
    int nTilesN) {
  constexpr int NT = K / 32;  // K-tiles; >= 8, even
  // slot: A 256x32 swizzled (8192 u16) | B 256x32 swizzled (8192 u16) = 32KB
  __shared__ u16 lds[4][16384];

  // bijective XCD-chunked swizzle (nwg % 8 == 0); consecutive lin share A-panel
  const int nwg = gridDim.x;
  const int chunk = nwg >> 3;
  const int bid = blockIdx.x;
  const int lin = (bid & 7) * chunk + (bid >> 3);
  const int nt = lin % nTilesN;
  const int mt = lin / nTilesN;
  const int m0 = mt * 256, n0 = nt * 256;
  const int N = nTilesN * 256;

  const int tid = threadIdx.x;
  const int lane = tid & 63;
  const int w = tid >> 6;   // 0..7
  const int wm = w >> 2;    // 0..1  (M half: 128 rows)
  const int wn = w & 3;     // 0..3  (N quarter: 64 cols)
  const int r16 = lane & 15, kq = lane >> 4;

  // ---- staging geometry (pre-swizzled global source, linear LDS dest) ----
  const int rt = tid >> 2;                            // row within round
  const int cg = (((tid & 3) << 3)) ^ (((rt >> 1) & 3) << 3);
  const u16* Ag = A + (size_t)(m0 + rt) * K + cg;
  const u16* Bg = Bt + (size_t)(n0 + rt) * K + cg;
  const int ldst = w * 512;  // wave-uniform; HW adds lane*16B

#define STAGE_AB(slot, kt)                                                    \
  {                                                                           \
    GLOAD_LDS16(Ag + (size_t)(kt) * 32, &lds[slot][ldst]);                    \
    GLOAD_LDS16(Ag + (size_t)(kt) * 32 + (size_t)128 * K,                     \
                &lds[slot][4096 + ldst]);                                     \
    GLOAD_LDS16(Bg + (size_t)(kt) * 32, &lds[slot][8192 + ldst]);             \
    GLOAD_LDS16(Bg + (size_t)(kt) * 32 + (size_t)128 * K,                     \
                &lds[slot][12288 + ldst]);                                    \
  }

  // ---- read-side swizzled offsets: elem (row,c) at row*32 + (c ^ (((row>>1)&3)<<3)) ----
  const int xk = (kq << 3) ^ (((r16 >> 1) & 3) << 3);
  const int aO = (wm * 128 + r16) * 32 + xk;          // + i*512
  const int bO = 8192 + (wn * 64 + r16) * 32 + xk;    // + j*512

  f32x4 acc[8][4] = {};
  bf16x8 r0_a[8], r0_b[4], r1_a[8], r1_b[4];  // two named operand sets (rule #20)

#define DSREAD(da, db, slot)                                                   \
  {                                                                            \
    const u16* sl = &lds[slot][0];                                             \
    _Pragma("unroll") for (int i = 0; i < 8; i++)                              \
        da[i] = *(const bf16x8*)&sl[aO + i * 512];                             \
    _Pragma("unroll") for (int j = 0; j < 4; j++)                              \
        db[j] = *(const bf16x8*)&sl[bO + j * 512];                             \
  }

#define MFMA_SET(sa, sb)                                                       \
  {                                                                            \
    __builtin_amdgcn_s_setprio(1);                                             \
    _Pragma("unroll") for (int i = 0; i < 8; i++)                              \
        _Pragma("unroll") for (int j = 0; j < 4; j++)                          \
            acc[i][j] = __builtin_amdgcn_mfma_f32_16x16x32_bf16(               \
                sa[i], sb[j], acc[i][j], 0, 0, 0);                             \
    __builtin_amdgcn_s_setprio(0);                                             \
  }

  // Compute tile t from (sa,sb) while reading tile t+1 into (da,db).
#define MFMA_RD(sa, sb, da, db, slot)                                          \
  {                                                                            \
    const u16* sl = &lds[slot][0];                                             \
    __builtin_amdgcn_s_setprio(1);                                             \
    _Pragma("unroll") for (int j = 0; j < 4; j++)                              \
        db[j] = *(const bf16x8*)&sl[bO + j * 512];                             \
    _Pragma("unroll") for (int i = 0; i < 8; i++) {                            \
      da[i] = *(const bf16x8*)&sl[aO + i * 512];                               \
      _Pragma("unroll") for (int j = 0; j < 4; j++)                            \
          acc[i][j] = __builtin_amdgcn_mfma_f32_16x16x32_bf16(                 \
              sa[i], sb[j], acc[i][j], 0, 0, 0);                               \
    }                                                                          \
    __builtin_amdgcn_s_setprio(0);                                             \
    __builtin_amdgcn_sched_group_barrier(0x100, 4, 0); /* 4 B ds_read */       \
    _Pragma("unroll") for (int i = 0; i < 8; i++) {                            \
      __builtin_amdgcn_sched_group_barrier(0x100, 1, 0); /* 1 A ds_read */     \
      __builtin_amdgcn_sched_group_barrier(0x8, 4, 0);   /* 4 MFMA */          \
    }                                                                          \
  }

#define SYNCB                                                                  \
  {                                                                            \
    __builtin_amdgcn_sched_barrier(0);                                         \
    __builtin_amdgcn_s_barrier();                                              \
    __builtin_amdgcn_sched_barrier(0);                                         \
  }

#define VM4 asm volatile("s_waitcnt vmcnt(4)" ::: "memory")
#define VM0 asm volatile("s_waitcnt vmcnt(0)" ::: "memory")

  // prologue: stage tiles 0,1,2; vmcnt(4) -> tiles 0,1 landed (tile2 in flight);
  // barrier; read tile0 into set0.
  STAGE_AB(0, 0);
  STAGE_AB(1, 1);
  STAGE_AB(2, 2);
  VM4;
  SYNCB;
  DSREAD(r0_a, r0_b, 0);

  // steady state, pairs (t, t+1), t <= NT-6:
  //   half A: STAGE(t+3); {MFMA tile t  || read t+1 -> set1}; VM4 (t+2 landed); barrier
  //   half B: STAGE(t+4); {MFMA tile t+1|| read t+2 -> set0}; VM4 (t+3 landed); barrier
  for (int t = 0; t + 6 <= NT; t += 2) {
    STAGE_AB((t + 3) & 3, t + 3);
    MFMA_RD(r0_a, r0_b, r1_a, r1_b, (t + 1) & 3);
    VM4;
    SYNCB;
    STAGE_AB((t + 4) & 3, t + 4);
    MFMA_RD(r1_a, r1_b, r0_a, r0_b, (t + 2) & 3);
    VM4;
    SYNCB;
  }
  // tail: tiles NT-4 .. NT-1
  STAGE_AB((NT - 1) & 3, NT - 1);          // last stage
  MFMA_RD(r0_a, r0_b, r1_a, r1_b, (NT - 3) & 3);  // tile NT-4, read NT-3
  VM4;                                     // tile NT-2 landed (only NT-1 in flight)
  SYNCB;
  MFMA_RD(r1_a, r1_b, r0_a, r0_b, (NT - 2) & 3);  // tile NT-3, read NT-2
  VM0;                                     // tile NT-1 landed
  SYNCB;
  MFMA_RD(r0_a, r0_b, r1_a, r1_b, (NT - 1) & 3);  // tile NT-2, read NT-1
  MFMA_SET(r1_a, r1_b);                    // tile NT-1
  SYNCB;                                   // frees LDS for the epilogue
#undef DSREAD
#undef MFMA_SET
#undef MFMA_RD
#undef SYNCB
#undef VM4
#undef VM0
#undef STAGE_AB

  // ---- epilogue: wave-local LDS transpose -> sector-dense coalesced bf16 stores ----
  float* fl = (float*)(&lds[0][0]) + w * 4096;
  const int zsel = SPLIT3 ? ((n0 + wn * 64) >> 9) : 0;
  u16* ob = SPLIT3 ? (u16*)((zsel == 0) ? out0 : (zsel == 1) ? out1 : out2)
                   : (u16*)out0;
  const int OC = SPLIT3 ? INNER : N;
  const int colloc = (lane & 7) * 8;
  const int gcol = (SPLIT3 ? ((n0 + wn * 64) & 511) : (n0 + wn * 64)) + colloc;
  const int lrowr = lane >> 3;
  float bvj[4];
#pragma unroll
  for (int j = 0; j < 4; j++) bvj[j] = bias[n0 + wn * 64 + j * 16 + r16];

#pragma unroll
  for (int pass = 0; pass < 4; ++pass) {
#pragma unroll
    for (int ii = 0; ii < 2; ++ii) {
#pragma unroll
      for (int j = 0; j < 4; ++j) {
#pragma unroll
        for (int q = 0; q < 4; ++q)
          fl[(ii * 16 + kq * 4 + q) * 68 + j * 16 + r16] =
              acc[pass * 2 + ii][j][q] + bvj[j];
      }
    }
#pragma unroll
    for (int inst = 0; inst < 4; ++inst) {
      int lr = inst * 8 + lrowr;
      float4 f0 = *(float4*)&fl[lr * 68 + colloc];
      float4 f1 = *(float4*)&fl[lr * 68 + colloc + 4];
      uint4 wv = {pack2(f0.x, f0.y), pack2(f0.z, f0.w),
                  pack2(f1.x, f1.y), pack2(f1.z, f1.w)};
      size_t grow = (size_t)(m0 + wm * 128 + pass * 32 + lr);
      *(uint4*)&ob[grow * OC + gcol] = wv;
    }
  }
}

// ---------------- legacy 128^2 GEMM (fp32 A staging) — small-ws fallback ----------------
template <bool A_BF16>
__global__ __launch_bounds__(256) void gemm128(
    const void* __restrict__ Aany, const u16* __restrict__ BtBase,
    const float* __restrict__ bias0, const float* __restrict__ bias1,
    const float* __restrict__ bias2,
    void* __restrict__ out0, void* __restrict__ out1, void* __restrict__ out2,
    int K) {
  __shared__ u16 As[128 * 32];
  __shared__ u16 Bs[128 * 32];
  const int N = gridDim.x * 128;
  const int z = blockIdx.z;
  const u16* Bt = BtBase + (size_t)z * N * K;
  const float* bias = (z == 0) ? bias0 : (z == 1) ? bias1 : bias2;
  void* Out = (z == 0) ? out0 : (z == 1) ? out1 : out2;
  const int tid = threadIdx.x;
  const int m0 = blockIdx.y * 128;
  const int n0 = blockIdx.x * 128;
  const int lane = tid & 63;
  const int wid = tid >> 6;
  const int wm = wid >> 1, wn = wid & 1;
  const int r16 = lane & 15, kq = lane >> 4;
  const int r = tid >> 1;
  const int half = tid & 1;
  f32x4 acc[4][4] = {};
  for (int k0 = 0; k0 < K; k0 += 32) {
    __syncthreads();
    if (A_BF16) {
      const u16* Ab = (const u16*)Aany;
      const int4* src = (const int4*)(Ab + (size_t)(m0 + r) * K + k0 + half * 16);
      int4 v0 = src[0];
      int4 v1 = src[1];
      *(int4*)&As[r * 32 + half * 16] = v0;
      *(int4*)&As[r * 32 + half * 16 + 8] = v1;
    } else {
      const float* Af = (const float*)Aany;
      const float4* src = (const float4*)(Af + (size_t)(m0 + r) * K + k0 + half * 16);
      float4 f0 = src[0], f1 = src[1], f2 = src[2], f3 = src[3];
      uint4 w0 = {pack2(f0.x, f0.y), pack2(f0.z, f0.w), pack2(f1.x, f1.y), pack2(f1.z, f1.w)};
      uint4 w1 = {pack2(f2.x, f2.y), pack2(f2.z, f2.w), pack2(f3.x, f3.y), pack2(f3.z, f3.w)};
      *(uint4*)&As[r * 32 + half * 16] = w0;
      *(uint4*)&As[r * 32 + half * 16 + 8] = w1;
    }
    {
      const int4* src = (const int4*)(Bt + (size_t)(n0 + r) * K + k0 + half * 16);
      int4 v0 = src[0];
      int4 v1 = src[1];
      *(int4*)&Bs[r * 32 + half * 16] = v0;
      *(int4*)&Bs[r * 32 + half * 16 + 8] = v1;
    }
    __syncthreads();
    bf16x8 a[4], b[4];
#pragma unroll
    for (int i = 0; i < 4; i++)
      a[i] = *(const bf16x8*)&As[(wm * 64 + i * 16 + r16) * 32 + kq * 8];
#pragma unroll
    for (int j = 0; j < 4; j++)
      b[j] = *(const bf16x8*)&Bs[(wn * 64 + j * 16 + r16) * 32 + kq * 8];
#pragma unroll
    for (int i = 0; i < 4; i++)
#pragma unroll
      for (int j = 0; j < 4; j++)
        acc[i][j] = __builtin_amdgcn_mfma_f32_16x16x32_bf16(a[i], b[j], acc[i][j], 0, 0, 0);
  }
#pragma unroll
  for (int j = 0; j < 4; j++) {
    int col = n0 + wn * 64 + j * 16 + r16;
    float bv = bias[col];
#pragma unroll
    for (int i = 0; i < 4; i++) {
#pragma unroll
      for (int q = 0; q < 4; q++) {
        int row = m0 + wm * 64 + i * 16 + kq * 4 + q;
        float v = acc[i][j][q] + bv;
        ((u16*)Out)[(size_t)row * N + col] = f2b(v);
      }
    }
  }
}

// ---------------- attn: softmax over heads of (q.k)/8 ----------------
__global__ __launch_bounds__(256) void attn_kernel(
    const u16* __restrict__ qb, const u16* __restrict__ kb,
    float* __restrict__ attn) {
  int lane = threadIdx.x & 63;
  int wid = threadIdx.x >> 6;
  size_t t = (size_t)blockIdx.x * 4 + wid;
  int4 qv = *(const int4*)(qb + t * INNER + lane * 8);
  int4 kv = *(const int4*)(kb + t * INNER + lane * 8);
  const u16* qu = (const u16*)&qv;
  const u16* ku = (const u16*)&kv;
  float s = 0.f;
#pragma unroll
  for (int j = 0; j < 8; j++) s += b2f(qu[j]) * b2f(ku[j]);
  s += __shfl_xor(s, 1);
  s += __shfl_xor(s, 2);
  s += __shfl_xor(s, 4);
  s *= 0.125f;
  float mx = s;
  mx = fmaxf(mx, __shfl_xor(mx, 8));
  mx = fmaxf(mx, __shfl_xor(mx, 16));
  mx = fmaxf(mx, __shfl_xor(mx, 32));
  float e = __expf(s - mx);
  float sm = e;
  sm += __shfl_xor(sm, 8);
  sm += __shfl_xor(sm, 16);
  sm += __shfl_xor(sm, 32);
  float a = e / sm;
  if ((lane & 7) == 0) attn[t * HEADS + (lane >> 3)] = a;
}

// ---------------- scan ----------------
__global__ __launch_bounds__(512) void scan_phase1(
    const u16* __restrict__ vb, const float* __restrict__ attn,
    const float* __restrict__ alpha, float* __restrict__ ends) {
  int hd = threadIdx.x;
  int h = hd >> 6;
  int c = blockIdx.x, b = blockIdx.y;
  float decay = 1.f / (1.f + __expf(-alpha[hd]));
  float om = 1.f - decay;
  size_t base = (size_t)b * SEQ + (size_t)c * CHLEN;
  float st = 0.f;
#pragma unroll 8
  for (int i = 0; i < CHLEN; i++) {
    size_t t = base + i;
    float a = attn[t * HEADS + h];
    float v = b2f(vb[t * INNER + hd]);
    st = decay * st + om * a * v;
  }
  ends[((size_t)b * NCHUNK + c) * INNER + hd] = st;
}

__global__ __launch_bounds__(512) void scan_phase2(
    const float* __restrict__ ends, const float* __restrict__ alpha,
    float* __restrict__ carries) {
  int hd = threadIdx.x;
  int b = blockIdx.x;
  float decay = 1.f / (1.f + __expf(-alpha[hd]));
  float dL = __powf(decay, (float)CHLEN);
  float carry = 0.f;
#pragma unroll 8
  for (int c = 0; c < NCHUNK; c++) {
    size_t idx = ((size_t)b * NCHUNK + c) * INNER + hd;
    carries[idx] = carry;
    carry = dL * carry + ends[idx];
  }
}

__global__ __launch_bounds__(512) void scan_phase3(
    const u16* __restrict__ qb, const u16* __restrict__ vb,
    const float* __restrict__ attn, const float* __restrict__ alpha,
    const float* __restrict__ augp, const float* __restrict__ carries,
    u16* __restrict__ outpre) {
  int hd = threadIdx.x;
  int h = hd >> 6;
  int c = blockIdx.x, b = blockIdx.y;
  float decay = 1.f / (1.f + __expf(-alpha[hd]));
  float om = 1.f - decay;
  float ap = augp[hd];
  float st = carries[((size_t)b * NCHUNK + c) * INNER + hd];
  size_t base = (size_t)b * SEQ + (size_t)c * CHLEN;
#pragma unroll 4
  for (int i = 0; i < CHLEN; i++) {
    size_t t = base + i;
    float a = attn[t * HEADS + h];
    float v = b2f(vb[t * INNER + hd]);
    st = decay * st + om * a * v;
    float q = b2f(qb[t * INNER + hd]);
    float aug = 1.f / (1.f + __expf(-q * ap));
    outpre[t * INNER + hd] = f2b(q * st + aug);
  }
}

// ---------------- LayerNorm: bf16 in -> fp32 out ----------------
__global__ __launch_bounds__(256) void ln_kernel(
    const u16* __restrict__ outln, float* __restrict__ out,
    const float* __restrict__ lns, const float* __restrict__ lnb) {
  size_t row = blockIdx.x;
  int tid = threadIdx.x;
  uint2 rv = *(const uint2*)(outln + row * HIDDEN + tid * 4);
  const u16* p = (const u16*)&rv;
  float v0 = b2f(p[0]), v1 = b2f(p[1]), v2 = b2f(p[2]), v3 = b2f(p[3]);
  float s = v0 + v1 + v2 + v3;
  float ss = v0 * v0 + v1 * v1 + v2 * v2 + v3 * v3;
#pragma unroll
  for (int m = 1; m < 64; m <<= 1) {
    s += __shfl_xor(s, m);
    ss += __shfl_xor(ss, m);
  }
  __shared__ float sb[4], ssb[4];
  int lane = tid & 63, wid = tid >> 6;
  if (lane == 0) {
    sb[wid] = s;
    ssb[wid] = ss;
  }
  __syncthreads();
  s = sb[0] + sb[1] + sb[2] + sb[3];
  ss = ssb[0] + ssb[1] + ssb[2] + ssb[3];
  float mean = s * (1.f / HIDDEN);
  float var = ss * (1.f / HIDDEN) - mean * mean;
  float rstd = rsqrtf(var + 1e-6f);
  float4 sc = *(const float4*)(lns + tid * 4);
  float4 bi = *(const float4*)(lnb + tid * 4);
  float4 o;
  o.x = (v0 - mean) * rstd * sc.x + bi.x;
  o.y = (v1 - mean) * rstd * sc.y + bi.y;
  o.z = (v2 - mean) * rstd * sc.z + bi.z;
  o.w = (v3 - mean) * rstd * sc.w + bi.w;
  *(float4*)(out + row * HIDDEN + tid * 4) = o;
}

extern "C" void kernel_launch(void* const* d_in, const int* in_sizes, int n_in,
                              void* d_out, int out_size, void* d_ws, size_t ws_size,
                              hipStream_t stream) {
  const float* x = (const float*)d_in[0];
  const float* Wq = (const float*)d_in[1];
  const float* bq = (const float*)d_in[2];
  const float* Wk = (const float*)d_in[3];
  const float* bk = (const float*)d_in[4];
  const float* Wv = (const float*)d_in[5];
  const float* bv = (const float*)d_in[6];
  const float* Wo = (const float*)d_in[7];
  const float* bo = (const float*)d_in[8];
  const float* alpha = (const float*)d_in[9];
  const float* augp = (const float*)d_in[10];
  const float* lns = (const float*)d_in[11];
  const float* lnb = (const float*)d_in[12];

  char* ws = (char*)d_ws;
  const bool fast = ws_size >= 175118336ull;

  if (fast) {
    u16* xb = (u16*)(ws + 0);                 // 67.1 MB (reused as outln)
    u16* qb = (u16*)(ws + 67108864);          // 33.5 MB
    u16* kb = (u16*)(ws + 100663296);         // 33.5 MB (reused as outpre)
    u16* vb = (u16*)(ws + 134217728);         // 33.5 MB
    u16* Wt = (u16*)(ws + 167772160);         // 3 MB, [1536][1024]
    u16* Wot = (u16*)(ws + 170917888);        // 1 MB, [1024][512]
    float* bcat = (float*)(ws + 171966464);   // 6 KB
    float* attn = (float*)(ws + 171972608);   // 1 MB
    float* ends = (float*)(ws + 173021184);   // 1 MB
    float* car = (float*)(ws + 174069760);    // 1 MB
    u16* outpre = kb;
    u16* outln = xb;  // xb dead after QKV gemm

    prep_xw<<<24576, 256, 0, stream>>>(x, xb, Wq, Wk, Wv, Wo, bq, bk, bv,
                                       Wt, Wot, bcat);

    // QKV: M=32768, N=1536 -> 128*6 = 768 blocks of 512 thr
    gemm_rp<HIDDEN, true><<<768, 512, 0, stream>>>(
        xb, Wt, bcat, qb, kb, vb, 6);

    attn_kernel<<<ROWS / 4, 256, 0, stream>>>(qb, kb, attn);
    scan_phase1<<<dim3(NCHUNK, BATCH), 512, 0, stream>>>(vb, attn, alpha, ends);
    scan_phase2<<<BATCH, 512, 0, stream>>>(ends, alpha, car);
    scan_phase3<<<dim3(NCHUNK, BATCH), 512, 0, stream>>>(qb, vb, attn, alpha, augp, car, outpre);

    // out: M=32768, N=1024 -> 128*4 = 512 blocks, bf16 -> outln
    gemm_rp<INNER, false><<<512, 512, 0, stream>>>(
        outpre, Wot, bo, outln, outln, outln, 4);

    ln_kernel<<<ROWS, 256, 0, stream>>>(outln, (float*)d_out, lns, lnb);
  } else {
    // fallback layout (108 MB): qb@0, vb@33.5, kb@67 (outpre); outln spans qb+vb
    u16* qb = (u16*)(ws + 0);
    u16* vb = (u16*)(ws + 33554432);
    u16* kb = (u16*)(ws + 67108864);
    u16* Wt = (u16*)(ws + 100663296);
    u16* Wot = (u16*)(ws + 103809024);
    float* bcat = (float*)(ws + 104845312);
    float* attn = (float*)(ws + 104857600);
    float* ends = (float*)(ws + 105906176);
    float* car = (float*)(ws + 106954752);
    u16* outpre = kb;
    u16* outln = (u16*)(ws + 0);  // qb+vb dead after scan3

    prep_w<<<8192, 256, 0, stream>>>(Wq, Wk, Wv, Wo, bq, bk, bv, Wt, Wot, bcat);
    gemm128<false><<<dim3(4, 256, 3), 256, 0, stream>>>(
        x, Wt, bq, bk, bv, qb, kb, vb, HIDDEN);
    attn_kernel<<<ROWS / 4, 256, 0, stream>>>(qb, kb, attn);
    scan_phase1<<<dim3(NCHUNK, BATCH), 512, 0, stream>>>(vb, attn, alpha, ends);
    scan_phase2<<<BATCH, 512, 0, stream>>>(ends, alpha, car);
    scan_phase3<<<dim3(NCHUNK, BATCH), 512, 0, stream>>>(qb, vb, attn, alpha, augp, car, outpre);
    gemm_rp<INNER, false><<<512, 512, 0, stream>>>(
        outpre, Wot, bo, outln, outln, outln, 4);
    ln_kernel<<<ROWS, 256, 0, stream>>>(outln, (float*)d_out, lns, lnb);
  }
}